// Round 1
// baseline (418.403 us; speedup 1.0000x reference)
//
#include <hip/hip_runtime.h>

#define B_ 512
#define T_ 1024
#define N_ 64
#define NA_ 66   // A is (N+2) x (N+2)
#define PF 4     // prefetch depth (P rows)

__global__ __launch_bounds__(64) void crf_fwd(
    const int* __restrict__ y,      // [B,T]
    const float* __restrict__ P,    // [B,T,N]
    const int* __restrict__ lens,   // [B]
    const float* __restrict__ A,    // [NA,NA]
    float* __restrict__ out)        // [B]
{
    const int b = blockIdx.x;
    const int j = threadIdx.x;            // 0..63, lane == state index
    const long pbase = (long)b * T_ * N_;
    const int ybase = b * T_;
    const int len = lens[b];              // in [T/2, T]

    // Column j of exp(Asub) held in registers: colA[i] = exp(A[i][j])
    float colA[N_];
#pragma unroll
    for (int i = 0; i < N_; ++i)
        colA[i] = __expf(A[i * NA_ + j]);

    __shared__ __align__(16) float ebuf[PF][N_];

    // t = 0 init: alpha0 = A[START,:] + P[:,0];  START = N_, END = N_+1
    const float p0 = P[pbase + j];
    const int y0 = y[ybase];
    float c = A[N_ * NA_ + j] + p0;   // centered alpha (M = 0)
    float M = 0.0f;                   // uniform offset, alpha = M + c
    float emit = (j == y0) ? p0 : 0.0f;

    // prefetch queue for P rows / y values
    float pq[PF];
    int yq[PF];
#pragma unroll
    for (int u = 0; u < PF; ++u) {
        const int t = 1 + u;
        const bool ok = (t < T_);
        pq[u] = ok ? P[pbase + t * N_ + j] : 0.0f;
        yq[u] = ok ? y[ybase + t] : 0;
    }

    // One scan step: new alpha_j = log( sum_i e^{c_i} expA[i][j] ) + M + P[t,j]
    auto step = [&](float pcur, int ycur, float* eb) {
        eb[j] = __expf(c);
        __syncthreads();   // single-wave block: cheap (waitcnt)
        float s0 = 0.f, s1 = 0.f, s2 = 0.f, s3 = 0.f;
#pragma unroll
        for (int i = 0; i < N_; i += 4) {
            const float4 ev = *reinterpret_cast<const float4*>(eb + i); // broadcast
            s0 = fmaf(ev.x, colA[i + 0], s0);
            s1 = fmaf(ev.y, colA[i + 1], s1);
            s2 = fmaf(ev.z, colA[i + 2], s2);
            s3 = fmaf(ev.w, colA[i + 3], s3);
        }
        const float S = (s0 + s1) + (s2 + s3);
        const float lS = __logf(S);
        // uniform recentering value: lane 0's logS (spread across j is <= 0.2)
        const float r = __int_as_float(
            __builtin_amdgcn_readfirstlane(__float_as_int(lS)));
        c = lS - r + pcur;
        M += r;
        emit += (j == ycur) ? pcur : 0.0f;
    };

    int t = 1;
    for (; t + PF <= len; t += PF) {
#pragma unroll
        for (int u = 0; u < PF; ++u) {
            // issue next prefetch before the dependent compute
            const int tp = t + u + PF;
            const bool ok = (tp < T_);
            const float pn = ok ? P[pbase + (long)tp * N_ + j] : 0.0f;
            const int yn = ok ? y[ybase + tp] : 0;
            step(pq[u], yq[u], ebuf[u]);
            pq[u] = pn;
            yq[u] = yn;
        }
    }
#pragma unroll
    for (int u = 0; u < PF; ++u) {
        if (t < len) {          // wave-uniform
            step(pq[u], yq[u], ebuf[u]);
            ++t;
        }
    }

    // ---- logZ = M + LSE_j(c_j + A[j, END]) ----
    float v = c + A[j * NA_ + (N_ + 1)];
    float mx = v;
#pragma unroll
    for (int off = 32; off >= 1; off >>= 1)
        mx = fmaxf(mx, __shfl_xor(mx, off, 64));
    float se = __expf(v - mx);
#pragma unroll
    for (int off = 32; off >= 1; off >>= 1)
        se += __shfl_xor(se, off, 64);
    const float logZ = M + mx + __logf(se);

    // ---- score ----
#pragma unroll
    for (int off = 32; off >= 1; off >>= 1)
        emit += __shfl_xor(emit, off, 64);

    float inner = 0.0f;
    for (int t0 = 1 + j; t0 < len; t0 += 64) {
        const int ya = y[ybase + t0 - 1];
        const int yb = y[ybase + t0];
        inner += A[ya * NA_ + yb];   // A is 17 KB -> L1/L2 resident
    }
#pragma unroll
    for (int off = 32; off >= 1; off >>= 1)
        inner += __shfl_xor(inner, off, 64);

    if (j == 0) {
        const float start = A[N_ * NA_ + y0];
        const int ylast = y[ybase + len - 1];
        const float endv = A[ylast * NA_ + (N_ + 1)];
        out[b] = logZ - (emit + start + inner + endv);
    }
}

extern "C" void kernel_launch(void* const* d_in, const int* in_sizes, int n_in,
                              void* d_out, int out_size, void* d_ws, size_t ws_size,
                              hipStream_t stream) {
    const int* y = (const int*)d_in[0];
    const float* P = (const float*)d_in[1];
    const int* lens = (const int*)d_in[2];
    const float* A = (const float*)d_in[3];
    float* out = (float*)d_out;
    crf_fwd<<<dim3(B_), dim3(64), 0, stream>>>(y, P, lens, A, out);
}

// Round 2
// 296.082 us; speedup vs baseline: 1.4131x; 1.4131x over previous
//
#include <hip/hip_runtime.h>

#define B_ 512
#define T_ 1024
#define N_ 64
#define NA_ 66
#define CH 8
#define LN2 0.69314718055994530942f

__global__ __launch_bounds__(64) void crf_fwd(
    const int* __restrict__ y,      // [B,T]
    const float* __restrict__ P,    // [B,T,N]
    const int* __restrict__ lens,   // [B]
    const float* __restrict__ A,    // [NA,NA]
    float* __restrict__ out)        // [B]
{
    const int b = blockIdx.x;
    const int j = threadIdx.x;                 // lane == state
    const long pbase = (long)b * (T_ * N_);
    const int yb = b * T_;
    const int len = lens[b];                   // in [T/2, T]

    // column j of exp(Asub): colA[i] = exp(A[i][j])
    float colA[N_];
#pragma unroll
    for (int i = 0; i < N_; ++i)
        colA[i] = __expf(A[i * NA_ + j]);

    __shared__ __align__(16) float zbuf[2][N_];

    // z-space state: alpha_j = log(z_j) + Mexp*ln2
    float z = __expf(A[N_ * NA_ + j] + P[pbase + j]);   // t=0 init
    int Mexp = 0;
    zbuf[0][j] = z;
    asm volatile("s_waitcnt lgkmcnt(0)" ::: "memory");

    // one scan step (wave-synchronous, no barrier)
    auto step = [&](float praw, float* rb, float* wb) {
        const float ep = __expf(praw);          // off the recursion chain
        float s0 = 0.f, s1 = 0.f, s2 = 0.f, s3 = 0.f;
#pragma unroll
        for (int i = 0; i < N_; i += 4) {
            const float4 q = *reinterpret_cast<const float4*>(rb + i); // broadcast
            s0 = fmaf(q.x, colA[i + 0], s0);
            s1 = fmaf(q.y, colA[i + 1], s1);
            s2 = fmaf(q.z, colA[i + 2], s2);
            s3 = fmaf(q.w, colA[i + 3], s3);
        }
        const float S = (s0 + s1) + (s2 + s3);
        // uniform renorm by exponent of lane0's S (spread across lanes <= e^12: safe)
        const int sb = __builtin_amdgcn_readfirstlane(__float_as_int(S));
        const int e0 = ((sb >> 23) & 0xff) - 127;
        z = ldexpf(S, -e0) * ep;
        Mexp += e0;
        wb[j] = z;
        asm volatile("s_waitcnt lgkmcnt(0)" ::: "memory");
    };

    const int nsteps = len - 1;                // >= 511
    const int nchunks = nsteps / CH;

    float prawA[CH], prawB[CH];

    auto issue = [&](int k, float (&dst)[CH]) { // load chunk k: steps t = 1+k*CH ..
#pragma unroll
        for (int u = 0; u < CH; ++u) {
            int t = 1 + k * CH + u;
            t = t < T_ ? t : T_ - 1;            // clamp; values beyond len unused
            dst[u] = P[pbase + t * N_ + j];
        }
    };

    auto runCH = [&](float (&src)[CH]) {
#pragma unroll
        for (int u = 0; u < CH; u += 2) {
            step(src[u],     zbuf[0], zbuf[1]);
            step(src[u + 1], zbuf[1], zbuf[0]);
        }
    };

    auto runTail = [&](float (&src)[CH], int tcnt) {
        float* rb = zbuf[0];
        float* wb = zbuf[1];
#pragma unroll
        for (int u = 0; u < CH; ++u) {
            if (u < tcnt) {                     // wave-uniform
                step(src[u], rb, wb);
                float* tmp = rb; rb = wb; wb = tmp;
            }
        }
    };

    issue(0, prawA);
    int c = 0;
    for (; c + 1 < nchunks; c += 2) {
        issue(c + 1, prawB);
        runCH(prawA);                            // chunk c
        issue(c + 2, prawA);
        runCH(prawB);                            // chunk c+1
    }
    if (c < nchunks) {                           // nchunks odd: prawA holds chunk c
        issue(c + 1, prawB);
        runCH(prawA);
        runTail(prawB, nsteps - nchunks * CH);
    } else {                                     // nchunks even: chunk nchunks already in prawA
        runTail(prawA, nsteps - nchunks * CH);
    }

    // ---- logZ = Mexp*ln2 + log( sum_j z_j * exp(A[j,END]) ) ----
    float send = z * __expf(A[j * NA_ + (N_ + 1)]);
#pragma unroll
    for (int off = 32; off >= 1; off >>= 1)
        send += __shfl_xor(send, off, 64);
    const float logZ = (float)Mexp * LN2 + __logf(send);

    // ---- score (epilogue, batched gathers) ----
    const int NK = T_ / 64;                      // 16
    int yk[NK];
#pragma unroll
    for (int k = 0; k < NK; ++k) {
        const int t = j + 64 * k;                // t <= 1023 < T_: always safe
        yk[k] = y[yb + t];
    }
    float em = 0.f, inn = 0.f;
    int carry = 0;
#pragma unroll
    for (int k = 0; k < NK; ++k) {
        const int t = j + 64 * k;
        const bool v = t < len;
        em += v ? P[pbase + t * N_ + yk[k]] : 0.f;
        int yp = __shfl_up(yk[k], 1, 64);        // y[t-1] for j>0
        if (j == 0) yp = carry;                  // lane63 of previous k
        carry = __shfl(yk[k], 63, 64);
        inn += (v && t >= 1) ? A[yp * NA_ + yk[k]] : 0.f;
    }
#pragma unroll
    for (int off = 32; off >= 1; off >>= 1) {
        em  += __shfl_xor(em, off, 64);
        inn += __shfl_xor(inn, off, 64);
    }
    if (j == 0) {
        const int y0 = y[yb];
        const float start = A[N_ * NA_ + y0];
        const int ylast = y[yb + len - 1];
        const float endv = A[ylast * NA_ + (N_ + 1)];
        out[b] = logZ - (em + start + inn + endv);
    }
}

extern "C" void kernel_launch(void* const* d_in, const int* in_sizes, int n_in,
                              void* d_out, int out_size, void* d_ws, size_t ws_size,
                              hipStream_t stream) {
    const int* y = (const int*)d_in[0];
    const float* P = (const float*)d_in[1];
    const int* lens = (const int*)d_in[2];
    const float* A = (const float*)d_in[3];
    float* out = (float*)d_out;
    crf_fwd<<<dim3(B_), dim3(64), 0, stream>>>(y, P, lens, A, out);
}

// Round 4
// 152.304 us; speedup vs baseline: 2.7472x; 1.9440x over previous
//
#include <hip/hip_runtime.h>

#define B_ 512
#define T_ 1024
#define N_ 64
#define NA_ 66
#define CH 8
#define LN2 0.69314718055994530942f

typedef __attribute__((ext_vector_type(8))) short short8;
typedef __attribute__((ext_vector_type(4))) float f32x4;

__device__ __forceinline__ unsigned short bf16_rne(float f) {
    unsigned u = __float_as_uint(f);
    u += 0x7fffu + ((u >> 16) & 1u);
    return (unsigned short)(u >> 16);
}

__global__ __launch_bounds__(64) void crf_fwd(
    const int* __restrict__ y,      // [B,T]
    const float* __restrict__ P,    // [B,T,N]
    const int* __restrict__ lens,   // [B]
    const float* __restrict__ A,    // [NA,NA]
    float* __restrict__ out)        // [B]
{
    const int b = blockIdx.x;
    const int j = threadIdx.x;      // lane == state/column index
    const int g = j >> 4;           // 16-lane group (k-group for A/B frags)
    const int m = j & 15;
    const long pbase = (long)b * (T_ * N_);
    const int yb = b * T_;
    const int len = lens[b];        // in [T/2, T]

    // B-fragments of W = exp(Asub): Bf[cb][kh][e] = W[32*kh + 8*g + e][16*cb + m]
    // A and B share the same (g,e)->k map, so contraction is correct for any
    // consistent hardware k-permutation; C layout col=lane&15 is HW-verified.
    short8 Bf[4][2];
#pragma unroll
    for (int cb = 0; cb < 4; ++cb) {
        const int col = 16 * cb + m;
#pragma unroll
        for (int kh = 0; kh < 2; ++kh) {
#pragma unroll
            for (int e = 0; e < 8; ++e) {
                const int r = 32 * kh + 8 * g + e;
                Bf[cb][kh][e] = (short)bf16_rne(__expf(A[r * NA_ + col]));
            }
        }
    }

    __shared__ __align__(16) unsigned short zl[N_];   // z state (bf16)

    // t=0: z0 = exp(A[START,j] + P[b,0,j])
    float zown = __expf(A[N_ * NA_ + j] + P[pbase + j]);
    zl[j] = bf16_rne(zown);
    short8 a1, a2;
    __builtin_memcpy(&a1, (const void*)(zl + 8 * g), 16);       // z[8g..8g+7]
    __builtin_memcpy(&a2, (const void*)(zl + 32 + 8 * g), 16);  // z[32+8g..]

    int Mexp = 0;   // alpha_j = log(z_j) + Mexp*ln2

    // One scan step. renorm=false: deterministic 2^-6 scale (stable, off-chain).
    // renorm=true: direct in-chain exponent renorm (zero-delay feedback, stable).
    auto step = [&](float praw, bool renorm) {
        f32x4 c0 = {0.f, 0.f, 0.f, 0.f};
        f32x4 c1 = {0.f, 0.f, 0.f, 0.f};
        f32x4 c2 = {0.f, 0.f, 0.f, 0.f};
        f32x4 c3 = {0.f, 0.f, 0.f, 0.f};
        c0 = __builtin_amdgcn_mfma_f32_16x16x32_bf16(a1, Bf[0][0], c0, 0, 0, 0);
        c0 = __builtin_amdgcn_mfma_f32_16x16x32_bf16(a2, Bf[0][1], c0, 0, 0, 0);
        c1 = __builtin_amdgcn_mfma_f32_16x16x32_bf16(a1, Bf[1][0], c1, 0, 0, 0);
        c1 = __builtin_amdgcn_mfma_f32_16x16x32_bf16(a2, Bf[1][1], c1, 0, 0, 0);
        c2 = __builtin_amdgcn_mfma_f32_16x16x32_bf16(a1, Bf[2][0], c2, 0, 0, 0);
        c2 = __builtin_amdgcn_mfma_f32_16x16x32_bf16(a2, Bf[2][1], c2, 0, 0, 0);
        c3 = __builtin_amdgcn_mfma_f32_16x16x32_bf16(a1, Bf[3][0], c3, 0, 0, 0);
        c3 = __builtin_amdgcn_mfma_f32_16x16x32_bf16(a2, Bf[3][1], c3, 0, 0, 0);
        // own column j = 16*g + m: tile g, any C row (all rows identical)
        const float c01 = (g & 1) ? c1[0] : c0[0];
        const float c23 = (g & 1) ? c3[0] : c2[0];
        const float sel = (g & 2) ? c23 : c01;
        if (renorm) {
            const int sb = __builtin_amdgcn_readfirstlane(__float_as_int(c0[0]));
            const int e0 = ((sb >> 23) & 0xff) - 127;   // wave-uniform
            zown = ldexpf(sel, -e0) * __expf(praw);
            Mexp += e0;
        } else {
            zown = sel * (__expf(praw) * 0.015625f);    // exact 2^-6
            Mexp += 6;
        }
        zl[j] = bf16_rne(zown);
        __builtin_memcpy(&a1, (const void*)(zl + 8 * g), 16);
        __builtin_memcpy(&a2, (const void*)(zl + 32 + 8 * g), 16);
    };

    const int nsteps = len - 1;            // >= 511
    const int nchunks = nsteps / CH;

    float prawA[CH], prawB[CH];
    auto issue = [&](int k, float (&dst)[CH]) {
#pragma unroll
        for (int u = 0; u < CH; ++u) {
            int t = 1 + k * CH + u;
            t = t < T_ ? t : T_ - 1;       // clamp; beyond-len values unused
            dst[u] = P[pbase + t * N_ + j];
        }
    };
    auto runCH = [&](float (&src)[CH]) {
#pragma unroll
        for (int u = 0; u < CH; ++u)
            step(src[u], u == 0);
    };
    auto runTail = [&](float (&src)[CH], int tcnt) {
#pragma unroll
        for (int u = 0; u < CH; ++u)
            if (u < tcnt)                  // wave-uniform
                step(src[u], u == 0);
    };

    issue(0, prawA);
    int c = 0;
    for (; c + 1 < nchunks; c += 2) {
        issue(c + 1, prawB); runCH(prawA);
        issue(c + 2, prawA); runCH(prawB);
    }
    if (c < nchunks) {
        issue(c + 1, prawB); runCH(prawA);
        runTail(prawB, nsteps - nchunks * CH);
    } else {
        runTail(prawA, nsteps - nchunks * CH);
    }

    // ---- logZ = Mexp*ln2 + log( sum_j z_j * exp(A[j, END]) ) ----
    float send = zown * __expf(A[j * NA_ + (N_ + 1)]);
#pragma unroll
    for (int off = 32; off >= 1; off >>= 1)
        send += __shfl_xor(send, off, 64);
    const float logZ = (float)Mexp * LN2 + __logf(send);

    // ---- score (epilogue, batched gathers) ----
    const int NK = T_ / 64;                // 16
    int yk[NK];
#pragma unroll
    for (int k = 0; k < NK; ++k)
        yk[k] = y[yb + j + 64 * k];
    float em = 0.f, inn = 0.f;
    int carry = 0;
#pragma unroll
    for (int k = 0; k < NK; ++k) {
        const int t = j + 64 * k;
        const bool v = t < len;
        em += v ? P[pbase + t * N_ + yk[k]] : 0.f;
        int yp = __shfl_up(yk[k], 1, 64);
        if (j == 0) yp = carry;
        carry = __shfl(yk[k], 63, 64);
        inn += (v && t >= 1) ? A[yp * NA_ + yk[k]] : 0.f;
    }
#pragma unroll
    for (int off = 32; off >= 1; off >>= 1) {
        em  += __shfl_xor(em, off, 64);
        inn += __shfl_xor(inn, off, 64);
    }
    if (j == 0) {
        const int y0 = y[yb];
        const float start = A[N_ * NA_ + y0];
        const int ylast = y[yb + len - 1];
        const float endv = A[ylast * NA_ + (N_ + 1)];
        out[b] = logZ - (em + start + inn + endv);
    }
}

extern "C" void kernel_launch(void* const* d_in, const int* in_sizes, int n_in,
                              void* d_out, int out_size, void* d_ws, size_t ws_size,
                              hipStream_t stream) {
    const int* y = (const int*)d_in[0];
    const float* P = (const float*)d_in[1];
    const int* lens = (const int*)d_in[2];
    const float* A = (const float*)d_in[3];
    float* out = (float*)d_out;
    crf_fwd<<<dim3(B_), dim3(64), 0, stream>>>(y, P, lens, A, out);
}